// Round 3
// baseline (213.061 us; speedup 1.0000x reference)
//
#include <hip/hip_runtime.h>

// Problem constants
#define NPTS 100000
#define NCH 32      // n
#define KNB 32      // K
#define MCL 16      // M

constexpr int IB1  = 128;   // i-blocks in encoder partial kernel
constexpr int SBLK = 512;   // blocks in S-partial kernel
constexpr int STILE = 64;   // points per LDS tile in S kernel

// Workspace layout (bytes) — all offsets 16B-aligned
constexpr size_t OFF_ENC_PART = 0;                          // 32*128 doubles = 32768
constexpr size_t OFF_ENC      = 32768;                      // 32 doubles     = 256
constexpr size_t OFF_INVW2    = OFF_ENC + 256;              // 512 floats     = 2048
constexpr size_t OFF_INVS     = OFF_INVW2 + 2048;           // 1024 floats    = 4096
constexpr size_t OFF_SPART    = OFF_INVS + 4096;            // 512*1024 dbl   = 4194304
constexpr size_t OFF_GT       = OFF_SPART + 4194304;        // N*32 floats    = 12800000

// ---------------------------------------------------------------------------
// Kernel 1: encoder matvec partials. encoded[j] = sum_i enc_w[j,i]*x[i]
__global__ __launch_bounds__(256) void k_enc_partial(
    const float* __restrict__ x, const float* __restrict__ enc_w,
    double* __restrict__ part) {
  int jg = blockIdx.x & 3;
  int ib = blockIdx.x >> 2;
  int j0 = jg * 8;
  int tid = threadIdx.x;
  double acc[8];
#pragma unroll
  for (int jj = 0; jj < 8; ++jj) acc[jj] = 0.0;
  for (int i = ib * 256 + tid; i < NPTS; i += IB1 * 256) {
    float xv = x[i];
#pragma unroll
    for (int jj = 0; jj < 8; ++jj)
      acc[jj] += (double)enc_w[(size_t)(j0 + jj) * NPTS + i] * (double)xv;
  }
#pragma unroll
  for (int jj = 0; jj < 8; ++jj) {
    double v = acc[jj];
#pragma unroll
    for (int off = 32; off >= 1; off >>= 1) v += __shfl_down(v, off);
    acc[jj] = v;
  }
  __shared__ double sw[4][8];
  int lane = tid & 63, w = tid >> 6;
  if (lane == 0)
    for (int jj = 0; jj < 8; ++jj) sw[w][jj] = acc[jj];
  __syncthreads();
  if (tid < 8) {
    double s = sw[0][tid] + sw[1][tid] + sw[2][tid] + sw[3][tid];
    part[(size_t)(j0 + tid) * IB1 + ib] = s;
  }
}

// ---------------------------------------------------------------------------
// Kernel 2: reduce encoder partials; bandwidths = bw_w@encoded + bw_b;
// invw2[m*32+j] = 1/w^2  (MU=1). One block, 512 threads (one per bw row).
__global__ __launch_bounds__(512) void k_head(
    const double* __restrict__ part, const float* __restrict__ enc_b,
    const float* __restrict__ bw_w, const float* __restrict__ bw_b,
    double* __restrict__ enc_out, float* __restrict__ invw2) {
  __shared__ double es[32];
  int tid = threadIdx.x;
  if (tid < 32) {
    double s = 0.0;
    for (int ib = 0; ib < IB1; ++ib) s += part[(size_t)tid * IB1 + ib];
    s += (double)enc_b[tid];
    enc_out[tid] = s;
    es[tid] = s;
  }
  __syncthreads();
  int r = tid;  // bw row = j*16 + m
  double wd = 0.0;
  for (int c = 0; c < 32; ++c) wd += (double)bw_w[r * 32 + c] * es[c];
  wd += (double)bw_b[r];
  int j = r >> 4, m = r & 15;
  invw2[m * 32 + j] = (float)(1.0 / (wd * wd));
}

// ---------------------------------------------------------------------------
// Kernel 3: gT[i*32+j] = (float)enc[j] * decoder[j*N+i]
__global__ __launch_bounds__(256) void k_gt(
    const float* __restrict__ decoder, const double* __restrict__ enc,
    float* __restrict__ gT) {
  __shared__ float tile[32][33];
  __shared__ float ef[32];
  int tx = threadIdx.x & 31, ty = threadIdx.x >> 5;  // ty: 0..7
  if (threadIdx.x < 32) ef[threadIdx.x] = (float)enc[threadIdx.x];
  int i0 = blockIdx.x * 32;
  for (int jj = ty; jj < 32; jj += 8)
    tile[tx][jj] = decoder[(size_t)jj * NPTS + i0 + tx];
  __syncthreads();
  for (int ii = ty; ii < 32; ii += 8)
    gT[(size_t)(i0 + ii) * 32 + tx] = tile[ii][tx] * ef[tx];
}

// ---------------------------------------------------------------------------
// Kernel 4 v2: S[j,k] partials. 256 threads: thread = (j = tid>>3, kq = tid&7)
// owns k = kq*4..kq*4+3. Per point: 1 ds_read_b128 (negated d2 quad) + 1
// broadcast ds_read_b32 (ic) covers 4 terms -> 4x fewer LDS instrs than v1.
__global__ __launch_bounds__(256) void k_spart(
    const float* __restrict__ nd, const int* __restrict__ labels,
    const float* __restrict__ invw2, double* __restrict__ spart) {
  __shared__ float iw[512];
  __shared__ __align__(16) float d2t[STILE * 32];  // negated d^2, k-contiguous
  __shared__ float ict[STILE * 32];                // iw[lab[i]*32+j], j-contiguous
  int tid = threadIdx.x;
  for (int q = tid; q < 512; q += 256) iw[q] = invw2[q];
  int j = tid >> 3, kq = tid & 7;
  double a0 = 0.0, a1 = 0.0, a2 = 0.0, a3 = 0.0;
  const int ntiles = (NPTS + STILE - 1) / STILE;  // 1563
  for (int tile = blockIdx.x; tile < ntiles; tile += SBLK) {
    int i0 = tile * STILE;
    __syncthreads();  // prev tile's readers done (also covers iw staging)
#pragma unroll
    for (int q = tid; q < STILE * 32; q += 256) {
      int ii = q >> 5;
      int gi = i0 + ii;
      float v = (gi < NPTS) ? nd[(size_t)i0 * 32 + q] : 1.0e18f;
      d2t[q] = -v * v;  // -1e36 for invalid -> relu term = 0
      int lab = (gi < NPTS) ? labels[gi] : 0;
      ict[q] = iw[lab * 32 + (q & 31)];
    }
    __syncthreads();
    float t0 = 0.0f, t1 = 0.0f, t2 = 0.0f, t3 = 0.0f;
#pragma unroll 8
    for (int ii = 0; ii < STILE; ++ii) {
      float icv = ict[ii * 32 + j];
      float4 d2 = *(const float4*)&d2t[ii * 32 + kq * 4];
      t0 += fmaxf(fmaf(d2.x, icv, 1.0f), 0.0f);
      t1 += fmaxf(fmaf(d2.y, icv, 1.0f), 0.0f);
      t2 += fmaxf(fmaf(d2.z, icv, 1.0f), 0.0f);
      t3 += fmaxf(fmaf(d2.w, icv, 1.0f), 0.0f);
    }
    a0 += (double)t0; a1 += (double)t1; a2 += (double)t2; a3 += (double)t3;
  }
  size_t base = (size_t)blockIdx.x * 1024 + j * 32 + kq * 4;
  spart[base + 0] = a0;
  spart[base + 1] = a1;
  spart[base + 2] = a2;
  spart[base + 3] = a3;
}

// ---------------------------------------------------------------------------
// Kernel 5: reduce S partials -> invS[k*32+j] (f32). 4 blocks x 256.
__global__ __launch_bounds__(256) void k_sreduce(
    const double* __restrict__ spart, float* __restrict__ invS) {
  int t = blockIdx.x * 256 + threadIdx.x;  // 0..1023 = j*32+k
  double s = 0.0;
  for (int b = 0; b < SBLK; ++b) s += spart[(size_t)b * 1024 + t];
  int j = t >> 5, k = t & 31;
  invS[k * 32 + j] = (float)(1.0 / s);
}

// ---------------------------------------------------------------------------
// Kernel 6 v3: one wave per point-pair, explicit load batching.
// lane l: q=l&7 -> j quad (j=q*4..q*4+3), g=l>>3 -> k in {g, g+8, g+16, g+24}.
// Phases per pair: all shfls -> all 8 dwordx4 gathers in flight -> math.
__global__ __launch_bounds__(256) void k_main(
    const float* __restrict__ nd, const int* __restrict__ nid,
    const int* __restrict__ labels, const float* __restrict__ gT,
    const float* __restrict__ invw2, const float* __restrict__ invS,
    float* __restrict__ out, int nwaves) {
  __shared__ __align__(16) float iw[512];
  __shared__ __align__(16) float is[1024];
  int tid = threadIdx.x;
  for (int qq = tid; qq < 512; qq += 256) iw[qq] = invw2[qq];
  for (int qq = tid; qq < 1024; qq += 256) is[qq] = invS[qq];
  __syncthreads();
  int lane = tid & 63;
  int w = tid >> 6;
  int q = lane & 7;
  int g = lane >> 3;
  int wid = blockIdx.x * 4 + w;
  // nwaves=10000: pairs (base, base+nwaves), base strided by 2*nwaves; 5 iters.
  for (int base = wid; base < NPTS; base += 2 * nwaves) {
    int i0 = base, i1 = base + nwaves;
    int lab0 = labels[i0], lab1 = labels[i1];
    int b0 = i0 * 32, b1 = i1 * 32;
    int myid0 = nid[b0 + (lane & 31)];
    float myd0 = nd[b0 + (lane & 31)];
    int myid1 = nid[b1 + (lane & 31)];
    float myd1 = nd[b1 + (lane & 31)];
    float4 iw0 = *(const float4*)&iw[lab0 * 32 + q * 4];
    float4 iw1 = *(const float4*)&iw[lab1 * 32 + q * 4];
    // Phase 1: broadcast ids/dists for my 4 k's (both points)
    int id0[4], id1[4];
    float dv0[4], dv1[4];
#pragma unroll
    for (int kk = 0; kk < 4; ++kk) {
      int k = kk * 8 + g;
      id0[kk] = __shfl(myid0, k);
      dv0[kk] = __shfl(myd0, k);
      id1[kk] = __shfl(myid1, k);
      dv1[kk] = __shfl(myd1, k);
    }
    // Phase 2: issue all 8 gathers
    float4 gv0[4], gv1[4];
#pragma unroll
    for (int kk = 0; kk < 4; ++kk) {
      gv0[kk] = *(const float4*)&gT[(size_t)id0[kk] * 32 + q * 4];
      gv1[kk] = *(const float4*)&gT[(size_t)id1[kk] * 32 + q * 4];
    }
    // Phase 3: math
    double a0 = 0.0, a1 = 0.0;
#pragma unroll
    for (int kk = 0; kk < 4; ++kk) {
      int k = kk * 8 + g;
      float4 sv = *(const float4*)&is[k * 32 + q * 4];
      float md0 = -dv0[kk] * dv0[kk];
      float md1 = -dv1[kk] * dv1[kk];
      float u0 = fmaxf(fmaf(md0, iw0.x, 1.0f), 0.0f);
      float u1 = fmaxf(fmaf(md0, iw0.y, 1.0f), 0.0f);
      float u2 = fmaxf(fmaf(md0, iw0.z, 1.0f), 0.0f);
      float u3 = fmaxf(fmaf(md0, iw0.w, 1.0f), 0.0f);
      a0 += (double)(gv0[kk].x * (u0 * sv.x));
      a0 += (double)(gv0[kk].y * (u1 * sv.y));
      a0 += (double)(gv0[kk].z * (u2 * sv.z));
      a0 += (double)(gv0[kk].w * (u3 * sv.w));
      float w0 = fmaxf(fmaf(md1, iw1.x, 1.0f), 0.0f);
      float w1 = fmaxf(fmaf(md1, iw1.y, 1.0f), 0.0f);
      float w2 = fmaxf(fmaf(md1, iw1.z, 1.0f), 0.0f);
      float w3 = fmaxf(fmaf(md1, iw1.w, 1.0f), 0.0f);
      a1 += (double)(gv1[kk].x * (w0 * sv.x));
      a1 += (double)(gv1[kk].y * (w1 * sv.y));
      a1 += (double)(gv1[kk].z * (w2 * sv.z));
      a1 += (double)(gv1[kk].w * (w3 * sv.w));
    }
#pragma unroll
    for (int off = 32; off >= 1; off >>= 1) {
      a0 += __shfl_down(a0, off);
      a1 += __shfl_down(a1, off);
    }
    if (lane == 0) {
      out[i0] = (float)a0;
      out[i1] = (float)a1;
    }
  }
}

// ---------------------------------------------------------------------------
extern "C" void kernel_launch(void* const* d_in, const int* in_sizes, int n_in,
                              void* d_out, int out_size, void* d_ws,
                              size_t ws_size, hipStream_t stream) {
  const float* x       = (const float*)d_in[0];
  const float* enc_w   = (const float*)d_in[1];
  const float* enc_b   = (const float*)d_in[2];
  const float* decoder = (const float*)d_in[3];
  const float* bw_w    = (const float*)d_in[4];
  const float* bw_b    = (const float*)d_in[5];
  const float* nd      = (const float*)d_in[6];
  const int*   nid     = (const int*)d_in[7];
  const int*   labels  = (const int*)d_in[8];
  float* out = (float*)d_out;

  char* ws = (char*)d_ws;
  double* part  = (double*)(ws + OFF_ENC_PART);
  double* enc_d = (double*)(ws + OFF_ENC);
  float*  invw2 = (float*)(ws + OFF_INVW2);
  float*  invS  = (float*)(ws + OFF_INVS);
  double* spart = (double*)(ws + OFF_SPART);
  float*  gT    = (float*)(ws + OFF_GT);

  hipLaunchKernelGGL(k_enc_partial, dim3(512), dim3(256), 0, stream, x, enc_w, part);
  hipLaunchKernelGGL(k_head, dim3(1), dim3(512), 0, stream, part, enc_b, bw_w, bw_b, enc_d, invw2);
  hipLaunchKernelGGL(k_gt, dim3(3125), dim3(256), 0, stream, decoder, enc_d, gT);
  hipLaunchKernelGGL(k_spart, dim3(SBLK), dim3(256), 0, stream, nd, labels, invw2, spart);
  hipLaunchKernelGGL(k_sreduce, dim3(4), dim3(256), 0, stream, spart, invS);
  // 2500 blocks x 4 waves = 10000 waves; pairs (i, i+10000); 5 iters/wave.
  hipLaunchKernelGGL(k_main, dim3(2500), dim3(256), 0, stream, nd, nid, labels, gT, invw2, invS, out, 10000);
}